// Round 6
// baseline (134.791 us; speedup 1.0000x reference)
//
#include <hip/hip_runtime.h>
#include <hip/hip_bf16.h>

#define D 128
#define BSH 6                 // bucket = row >> 6 (64 rows/bucket)
#define BROWS 64
#define CH 4096               // edges per agg chunk
#define APAD 264              // bf16 per A_lds row (16B-aligned: 264*2=528)

typedef __attribute__((ext_vector_type(8))) short bf16x8;
typedef __attribute__((ext_vector_type(8))) unsigned short ushort8;
typedef __attribute__((ext_vector_type(4))) float f32x4;

static __device__ __forceinline__ unsigned short f2bf(float f) {
    unsigned int u = __builtin_bit_cast(unsigned int, f);
    unsigned int r = (u + 0x7FFFu + ((u >> 16) & 1u)) >> 16;
    return (unsigned short)r;
}
static __device__ __forceinline__ float bf2f(unsigned short u) {
    return __builtin_bit_cast(float, ((unsigned int)u) << 16);
}

// ---- setup: x->bf16, Wcat, zero BN acc, per-block bucket histograms -------
__global__ __launch_bounds__(256) void setup_k(const float* __restrict__ x,
                                               const float* __restrict__ Wl,
                                               const float* __restrict__ Wr,
                                               const int* __restrict__ rowi,
                                               unsigned short* __restrict__ xbf,
                                               unsigned short* __restrict__ Wcat,
                                               int* __restrict__ gh,
                                               float* __restrict__ bn_acc,
                                               int N, int NB, int E, int eblocks) {
    __shared__ int hist[1024];
    int t = threadIdx.x;
    int gid = blockIdx.x * 256 + t;
    int stride = gridDim.x * 256;
    int total4 = N * D / 4;
    for (int i = gid; i < total4; i += stride) {
        float4 v = reinterpret_cast<const float4*>(x)[i];
        ushort4 o;
        o.x = f2bf(v.x); o.y = f2bf(v.y); o.z = f2bf(v.z); o.w = f2bf(v.w);
        reinterpret_cast<ushort4*>(xbf)[i] = o;
    }
    for (int i = gid; i < D * 2 * D; i += stride) {
        int o = i >> 8, k = i & 255;
        float v = (k < D) ? Wl[o * D + k] : Wr[o * D + (k - D)];
        Wcat[i] = f2bf(v);
    }
    if (gid < 2 * D) bn_acc[gid] = 0.f;

    // per-block histogram slice (no global atomics, no pre-zero needed)
    if (blockIdx.x < (unsigned)eblocks) {
        for (int i = t; i < NB; i += 256) hist[i] = 0;
        __syncthreads();
        int base = blockIdx.x * 8192;
        #pragma unroll
        for (int k = 0; k < 32; ++k) {
            int e = base + k * 256 + t;
            if (e < E) atomicAdd(&hist[rowi[e] >> BSH], 1);
        }
        __syncthreads();
        for (int i = t; i < NB; i += 256) gh[blockIdx.x * 1024 + i] = hist[i];
    }
}

// ---- scanB: sum histogram slices + exclusive scan (NB <= 1024) ------------
__global__ __launch_bounds__(1024) void scanB_k(const int* __restrict__ gh,
                                                int* __restrict__ bstart,
                                                int* __restrict__ gcur,
                                                int NB, int E, int eb) {
    __shared__ int lds[1024];
    int t = threadIdx.x;
    int v = 0;
    if (t < NB)
        for (int b = 0; b < eb; ++b) v += gh[b * 1024 + t];
    lds[t] = v;
    __syncthreads();
    #pragma unroll
    for (int off = 1; off < 1024; off <<= 1) {
        int u = (t >= off) ? lds[t - off] : 0;
        __syncthreads();
        lds[t] += u;
        __syncthreads();
    }
    if (t < NB) {
        int s = lds[t] - v;
        bstart[t] = s;
        gcur[t] = s;
    }
    if (t == 0) bstart[NB] = E;
}

// ---- binB: scatter edges into bucket regions, packed (row<<16)|col --------
__global__ __launch_bounds__(256) void binB_k(const int* __restrict__ rowi,
                                              const int* __restrict__ coli,
                                              int* __restrict__ gcur,
                                              unsigned int* __restrict__ binned,
                                              int E, int NB) {
    __shared__ unsigned int stage[8192];
    __shared__ int hist[1024];
    __shared__ int basep[1024];
    __shared__ int cur[1024];
    int t = threadIdx.x;
    for (int i = t; i < NB; i += 256) { hist[i] = 0; cur[i] = 0; }
    __syncthreads();
    int base = blockIdx.x * 8192;
    int cnt = E - base; if (cnt > 8192) cnt = 8192;
    #pragma unroll
    for (int k = 0; k < 32; ++k) {
        int i = k * 256 + t;
        if (i < cnt) {
            int r = rowi[base + i], c = coli[base + i];
            stage[i] = ((unsigned int)r << 16) | (unsigned int)c;
            atomicAdd(&hist[r >> BSH], 1);
        }
    }
    __syncthreads();
    for (int i = t; i < NB; i += 256) {
        int h = hist[i];
        basep[i] = h ? atomicAdd(&gcur[i], h) : 0;
    }
    __syncthreads();
    #pragma unroll
    for (int k = 0; k < 32; ++k) {
        int i = k * 256 + t;
        if (i < cnt) {
            unsigned int p = stage[i];
            int b = p >> (16 + BSH);
            int pos = basep[b] + atomicAdd(&cur[b], 1);
            binned[pos] = p;
        }
    }
}

// ---- aggemm: fused per-bucket sort + register agg + MFMA GEMM + BN --------
// block b owns nodes [b*64, b*64+64); 512 thr = 8 waves
// agg phase: wave w aggregates rows [w*8, w*8+8), lane owns 2 feature cols
// gemm phase: wave w computes output cols [w*16, w*16+16) for all 64 rows
__global__ __launch_bounds__(512) void aggemm_k(const unsigned short* __restrict__ xbf,
                                                const unsigned int* __restrict__ binned,
                                                const int* __restrict__ bstart,
                                                const unsigned short* __restrict__ Wcat,
                                                const float* __restrict__ bl,
                                                const float* __restrict__ br,
                                                unsigned short* __restrict__ hbf,
                                                float* __restrict__ bn_sum,
                                                float* __restrict__ bn_ss, int N) {
    __shared__ unsigned int sorted[CH];
    __shared__ int hist[BROWS];
    __shared__ int sincl[BROWS];
    __shared__ int sstart[BROWS + 1];
    __shared__ int scur[BROWS];
    __shared__ unsigned short A_lds[BROWS * APAD];
    __shared__ float bn_lds[2 * D];
    int t = threadIdx.x;
    int b = blockIdx.x;
    int s = bstart[b], e = bstart[b + 1];
    int w = t >> 6, lane = t & 63;
    int lr = lane & 15, lk = lane >> 4;

    if (t < 2 * D) bn_lds[t] = 0.f;

    // hoist B fragments (latency hidden under agg phase)
    bf16x8 Breg[8];
    #pragma unroll
    for (int ks = 0; ks < 8; ++ks)
        Breg[ks] = *reinterpret_cast<const bf16x8*>(
            &Wcat[(w * 16 + lr) * 256 + ks * 32 + lk * 8]);

    // ---------- agg phase ----------
    float a0[8], a1[8];
    #pragma unroll
    for (int i = 0; i < 8; ++i) { a0[i] = 0.f; a1[i] = 0.f; }
    const unsigned short* xb = xbf + lane * 2;

    for (int cs = s; cs < e; cs += CH) {
        int cnt = e - cs; if (cnt > CH) cnt = CH;
        if (t < BROWS) hist[t] = 0;
        __syncthreads();
        #pragma unroll
        for (int k = 0; k < CH / 512; ++k) {
            int i = k * 512 + t;
            if (i < cnt) atomicAdd(&hist[(binned[cs + i] >> 16) & (BROWS - 1)], 1);
        }
        __syncthreads();
        if (t < BROWS) sincl[t] = hist[t];
        __syncthreads();
        #pragma unroll
        for (int off = 1; off < BROWS; off <<= 1) {
            int u = 0;
            if (t < BROWS && t >= off) u = sincl[t - off];
            __syncthreads();
            if (t < BROWS) sincl[t] += u;
            __syncthreads();
        }
        if (t < BROWS) {
            int ex = sincl[t] - hist[t];
            sstart[t] = ex;
            scur[t] = ex;
        }
        if (t == 0) sstart[BROWS] = cnt;
        __syncthreads();
        #pragma unroll
        for (int k = 0; k < CH / 512; ++k) {
            int i = k * 512 + t;
            if (i < cnt) {
                unsigned int p = binned[cs + i];
                int pos = atomicAdd(&scur[(p >> 16) & (BROWS - 1)], 1);
                sorted[pos] = p;
            }
        }
        __syncthreads();
        #pragma unroll
        for (int i = 0; i < 8; ++i) {
            int r = w * 8 + i;
            int js = sstart[r], je = sstart[r + 1];
            float s0 = a0[i], s1 = a1[i];
            int j = js;
            for (; j + 4 <= je; j += 4) {
                unsigned int p0 = sorted[j], p1 = sorted[j + 1];
                unsigned int p2 = sorted[j + 2], p3 = sorted[j + 3];
                unsigned int v0 = *reinterpret_cast<const unsigned int*>(xb + (size_t)(p0 & 0xFFFFu) * D);
                unsigned int v1 = *reinterpret_cast<const unsigned int*>(xb + (size_t)(p1 & 0xFFFFu) * D);
                unsigned int v2 = *reinterpret_cast<const unsigned int*>(xb + (size_t)(p2 & 0xFFFFu) * D);
                unsigned int v3 = *reinterpret_cast<const unsigned int*>(xb + (size_t)(p3 & 0xFFFFu) * D);
                s0 += bf2f((unsigned short)v0) + bf2f((unsigned short)v1)
                    + bf2f((unsigned short)v2) + bf2f((unsigned short)v3);
                s1 += bf2f((unsigned short)(v0 >> 16)) + bf2f((unsigned short)(v1 >> 16))
                    + bf2f((unsigned short)(v2 >> 16)) + bf2f((unsigned short)(v3 >> 16));
            }
            for (; j < je; ++j) {
                unsigned int p = sorted[j];
                unsigned int v = *reinterpret_cast<const unsigned int*>(xb + (size_t)(p & 0xFFFFu) * D);
                s0 += bf2f((unsigned short)v);
                s1 += bf2f((unsigned short)(v >> 16));
            }
            a0[i] = s0; a1[i] = s1;
        }
        __syncthreads();
    }

    // ---------- stage A tile ----------
    // agg result -> cols [0,128)
    #pragma unroll
    for (int i = 0; i < 8; ++i) {
        int r = w * 8 + i;
        unsigned int o = (unsigned int)f2bf(a0[i]) | ((unsigned int)f2bf(a1[i]) << 16);
        *reinterpret_cast<unsigned int*>(&A_lds[r * APAD + lane * 2]) = o;
    }
    // own-row x -> cols [128,256)
    #pragma unroll
    for (int k = 0; k < 2; ++k) {
        int ch = k * 512 + t;          // 0..1023
        int r = ch >> 4;               // 0..63
        int c16 = ch & 15;             // 16B chunk
        int node = b * BROWS + r;
        ushort8 v = (ushort8){0, 0, 0, 0, 0, 0, 0, 0};
        if (node < N) v = *reinterpret_cast<const ushort8*>(&xbf[(size_t)node * D + c16 * 8]);
        *reinterpret_cast<ushort8*>(&A_lds[r * APAD + 128 + c16 * 8]) = v;
    }
    __syncthreads();

    // ---------- MFMA ----------
    f32x4 acc[4];
    #pragma unroll
    for (int m = 0; m < 4; ++m) acc[m] = (f32x4){0.f, 0.f, 0.f, 0.f};
    #pragma unroll
    for (int m = 0; m < 4; ++m)
        #pragma unroll
        for (int ks = 0; ks < 8; ++ks) {
            bf16x8 a = *reinterpret_cast<const bf16x8*>(
                &A_lds[(m * 16 + lr) * APAD + ks * 32 + lk * 8]);
            acc[m] = __builtin_amdgcn_mfma_f32_16x16x32_bf16(a, Breg[ks], acc[m], 0, 0, 0);
        }

    // ---------- epilogue: bias + relu + store bf16 h + BN partials ----------
    int colo = w * 16 + lr;
    float bias = bl[colo] + br[colo];
    float s1 = 0.f, s2 = 0.f;
    #pragma unroll
    for (int m = 0; m < 4; ++m)
        #pragma unroll
        for (int ee = 0; ee < 4; ++ee) {
            int node = b * BROWS + m * 16 + lk * 4 + ee;
            if (node < N) {
                float hv = acc[m][ee] + bias;
                hv = hv > 0.f ? hv : 0.f;
                hbf[(size_t)node * D + colo] = f2bf(hv);
                s1 += hv;
                s2 += hv * hv;
            }
        }
    atomicAdd(&bn_lds[colo], s1);
    atomicAdd(&bn_lds[D + colo], s2);
    __syncthreads();
    if (t < D) {
        atomicAdd(&bn_sum[t], bn_lds[t]);
        atomicAdd(&bn_ss[t], bn_lds[D + t]);
    }
}

// ---- bnfin: per-channel scale/shift ---------------------------------------
__global__ void bnfin_k(const float* __restrict__ bn_sum, const float* __restrict__ bn_ss,
                        const float* __restrict__ gamma, const float* __restrict__ beta,
                        float* __restrict__ scale, float* __restrict__ shift, float invN) {
    int d = threadIdx.x;
    float m = bn_sum[d] * invN;
    float v = bn_ss[d] * invN - m * m;
    float r = rsqrtf(v + 1e-5f);
    float sc = gamma[d] * r;
    scale[d] = sc;
    shift[d] = beta[d] - m * sc;
}

// ---- bnapply: out = h*scale + shift (h bf16 -> f32 out) -------------------
__global__ __launch_bounds__(256) void bnapply_k(const unsigned short* __restrict__ hbf,
                                                 float* __restrict__ out,
                                                 const float* __restrict__ scale,
                                                 const float* __restrict__ shift,
                                                 int total8) {
    int gid = blockIdx.x * 256 + threadIdx.x;
    if (gid >= total8) return;
    int d8 = (gid & 15) * 8;
    ushort8 hv = *reinterpret_cast<const ushort8*>(&hbf[(size_t)gid * 8]);
    float4 sc0 = *reinterpret_cast<const float4*>(scale + d8);
    float4 sc1 = *reinterpret_cast<const float4*>(scale + d8 + 4);
    float4 sh0 = *reinterpret_cast<const float4*>(shift + d8);
    float4 sh1 = *reinterpret_cast<const float4*>(shift + d8 + 4);
    float4 o0, o1;
    o0.x = bf2f((unsigned short)hv[0]) * sc0.x + sh0.x;
    o0.y = bf2f((unsigned short)hv[1]) * sc0.y + sh0.y;
    o0.z = bf2f((unsigned short)hv[2]) * sc0.z + sh0.z;
    o0.w = bf2f((unsigned short)hv[3]) * sc0.w + sh0.w;
    o1.x = bf2f((unsigned short)hv[4]) * sc1.x + sh1.x;
    o1.y = bf2f((unsigned short)hv[5]) * sc1.y + sh1.y;
    o1.z = bf2f((unsigned short)hv[6]) * sc1.z + sh1.z;
    o1.w = bf2f((unsigned short)hv[7]) * sc1.w + sh1.w;
    *reinterpret_cast<float4*>(out + (size_t)gid * 8) = o0;
    *reinterpret_cast<float4*>(out + (size_t)gid * 8 + 4) = o1;
}

extern "C" void kernel_launch(void* const* d_in, const int* in_sizes, int n_in,
                              void* d_out, int out_size, void* d_ws, size_t ws_size,
                              hipStream_t stream) {
    const float* x     = (const float*)d_in[0];
    const int*   ei    = (const int*)d_in[1];
    const float* Wl    = (const float*)d_in[2];
    const float* bl    = (const float*)d_in[3];
    const float* Wr    = (const float*)d_in[4];
    const float* br    = (const float*)d_in[5];
    const float* gamma = (const float*)d_in[6];
    const float* beta  = (const float*)d_in[7];
    int N = in_sizes[0] / D;
    int E = in_sizes[1] / 2;
    int NB = (N + BROWS - 1) / BROWS;    // 782 (must be <= 1024)
    int eblocks = (E + 8191) / 8192;     // 98

    float* ws = (float*)d_ws;
    float* bn_sum = ws;                                   // D
    float* bn_ss  = ws + D;                               // D
    float* scale  = ws + 2 * D;                           // D
    float* shift  = ws + 3 * D;                           // D
    unsigned short* xbf  = (unsigned short*)(ws + 4 * D); // N*D
    unsigned short* hbf  = xbf + (size_t)N * D;           // N*D
    unsigned short* Wcat = hbf + (size_t)N * D;           // 2*D*D
    int* gcur   = (int*)(Wcat + 2 * D * D);               // pad 1024
    int* bstart = gcur + 1024;                            // pad 1028
    int* gh     = bstart + 1028;                          // eblocks*1024
    unsigned int* binned = (unsigned int*)(gh + (size_t)eblocks * 1024); // E
    float* out = (float*)d_out;

    const int* rowi = ei;
    const int* coli = ei + E;

    setup_k<<<2048, 256, 0, stream>>>(x, Wl, Wr, rowi, xbf, Wcat, gh, bn_sum,
                                      N, NB, E, eblocks);
    scanB_k<<<1, 1024, 0, stream>>>(gh, bstart, gcur, NB, E, eblocks);
    binB_k<<<eblocks, 256, 0, stream>>>(rowi, coli, gcur, binned, E, NB);
    aggemm_k<<<NB, 512, 0, stream>>>(xbf, binned, bstart, Wcat, bl, br,
                                     hbf, bn_sum, bn_ss, N);
    bnfin_k<<<1, D, 0, stream>>>(bn_sum, bn_ss, gamma, beta, scale, shift,
                                 1.0f / (float)N);
    int total8 = N * D / 8;
    bnapply_k<<<(total8 + 255) / 256, 256, 0, stream>>>(hbf, out, scale, shift, total8);
}

// Round 7
// 117.051 us; speedup vs baseline: 1.1516x; 1.1516x over previous
//
#include <hip/hip_runtime.h>
#include <hip/hip_bf16.h>

#define D 128
#define BSH 6                 // bucket = row >> 6 (64 rows/bucket)
#define BROWS 64
#define CH 4096               // edges per agg chunk
#define AP 136                // padded bf16 row for A halves (128+8): 272B stride, conflict-free b128

typedef __attribute__((ext_vector_type(8))) short bf16x8;
typedef __attribute__((ext_vector_type(8))) unsigned short ushort8;
typedef __attribute__((ext_vector_type(4))) float f32x4;

static __device__ __forceinline__ unsigned short f2bf(float f) {
    unsigned int u = __builtin_bit_cast(unsigned int, f);
    unsigned int r = (u + 0x7FFFu + ((u >> 16) & 1u)) >> 16;
    return (unsigned short)r;
}
static __device__ __forceinline__ float bf2f(unsigned short u) {
    return __builtin_bit_cast(float, ((unsigned int)u) << 16);
}

// ---- setup: x->bf16, Wcat, zero BN acc, per-block bucket histograms -------
// ghT layout: [bucket][block-slot], slot stride 128 (eblocks <= 128)
__global__ __launch_bounds__(256) void setup_k(const float* __restrict__ x,
                                               const float* __restrict__ Wl,
                                               const float* __restrict__ Wr,
                                               const int* __restrict__ rowi,
                                               unsigned short* __restrict__ xbf,
                                               unsigned short* __restrict__ Wcat,
                                               int* __restrict__ ghT,
                                               float* __restrict__ bn_acc,
                                               int N, int NB, int E, int eblocks) {
    __shared__ int hist[1024];
    int t = threadIdx.x;
    int gid = blockIdx.x * 256 + t;
    int stride = gridDim.x * 256;
    int total4 = N * D / 4;
    for (int i = gid; i < total4; i += stride) {
        float4 v = reinterpret_cast<const float4*>(x)[i];
        ushort4 o;
        o.x = f2bf(v.x); o.y = f2bf(v.y); o.z = f2bf(v.z); o.w = f2bf(v.w);
        reinterpret_cast<ushort4*>(xbf)[i] = o;
    }
    for (int i = gid; i < D * 2 * D; i += stride) {
        int o = i >> 8, k = i & 255;
        float v = (k < D) ? Wl[o * D + k] : Wr[o * D + (k - D)];
        Wcat[i] = f2bf(v);
    }
    if (gid < 2 * D) bn_acc[gid] = 0.f;

    if (blockIdx.x < (unsigned)eblocks) {
        for (int i = t; i < NB; i += 256) hist[i] = 0;
        __syncthreads();
        int base = blockIdx.x * 8192;
        #pragma unroll
        for (int k = 0; k < 32; ++k) {
            int e = base + k * 256 + t;
            if (e < E) atomicAdd(&hist[rowi[e] >> BSH], 1);
        }
        __syncthreads();
        for (int i = t; i < NB; i += 256) ghT[i * 128 + blockIdx.x] = hist[i];
    }
}

// ---- scanB: sum transposed slices + exclusive scan (NB <= 1024) -----------
__global__ __launch_bounds__(1024) void scanB_k(const int* __restrict__ ghT,
                                                int* __restrict__ bstart,
                                                int* __restrict__ gcur,
                                                int NB, int E, int eb) {
    __shared__ int lds[1024];
    int t = threadIdx.x;
    int v = 0;
    if (t < NB) {
        const int* row = ghT + (size_t)t * 128;
        int b = 0;
        for (; b + 4 <= eb; b += 4) {
            int4 q = *reinterpret_cast<const int4*>(row + b);
            v += q.x + q.y + q.z + q.w;
        }
        for (; b < eb; ++b) v += row[b];
    }
    lds[t] = v;
    __syncthreads();
    #pragma unroll
    for (int off = 1; off < 1024; off <<= 1) {
        int u = (t >= off) ? lds[t - off] : 0;
        __syncthreads();
        lds[t] += u;
        __syncthreads();
    }
    if (t < NB) {
        int s = lds[t] - v;
        bstart[t] = s;
        gcur[t] = s;
    }
    if (t == 0) bstart[NB] = E;
}

// ---- binB: scatter edges into bucket regions, packed (row<<16)|col --------
__global__ __launch_bounds__(256) void binB_k(const int* __restrict__ rowi,
                                              const int* __restrict__ coli,
                                              int* __restrict__ gcur,
                                              unsigned int* __restrict__ binned,
                                              int E, int NB) {
    __shared__ unsigned int stage[8192];
    __shared__ int hist[1024];
    __shared__ int basep[1024];
    __shared__ int cur[1024];
    int t = threadIdx.x;
    for (int i = t; i < NB; i += 256) { hist[i] = 0; cur[i] = 0; }
    __syncthreads();
    int base = blockIdx.x * 8192;
    int cnt = E - base; if (cnt > 8192) cnt = 8192;
    #pragma unroll
    for (int k = 0; k < 32; ++k) {
        int i = k * 256 + t;
        if (i < cnt) {
            int r = rowi[base + i], c = coli[base + i];
            stage[i] = ((unsigned int)r << 16) | (unsigned int)c;
            atomicAdd(&hist[r >> BSH], 1);
        }
    }
    __syncthreads();
    for (int i = t; i < NB; i += 256) {
        int h = hist[i];
        basep[i] = h ? atomicAdd(&gcur[i], h) : 0;
    }
    __syncthreads();
    #pragma unroll
    for (int k = 0; k < 32; ++k) {
        int i = k * 256 + t;
        if (i < cnt) {
            unsigned int p = stage[i];
            int b = p >> (16 + BSH);
            int pos = basep[b] + atomicAdd(&cur[b], 1);
            binned[pos] = p;
        }
    }
}

// ---- aggemm: fused per-bucket sort + register agg + MFMA GEMM + BN --------
// block b owns nodes [b*64, b*64+64); 512 thr = 8 waves
// agg: wave w aggregates rows [w*8, w*8+8), lane owns 2 feature cols, unroll-8
// gemm: wave w computes output cols [w*16, w*16+16) for all 64 rows
__global__ __launch_bounds__(512) void aggemm_k(const unsigned short* __restrict__ xbf,
                                                const unsigned int* __restrict__ binned,
                                                const int* __restrict__ bstart,
                                                const unsigned short* __restrict__ Wcat,
                                                const float* __restrict__ bl,
                                                const float* __restrict__ br,
                                                unsigned short* __restrict__ hbf,
                                                float* __restrict__ bn_sum,
                                                float* __restrict__ bn_ss, int N) {
    __shared__ unsigned short A_agg[BROWS][AP];                 // 17408 B
    __shared__ __align__(16) unsigned char ubuf[BROWS * AP * 2]; // A_x / sorted union
    __shared__ int hist[BROWS];
    __shared__ int sincl[BROWS];
    __shared__ int sstart[BROWS + 1];
    __shared__ int scur[BROWS];
    __shared__ float bn_lds[2 * D];

    unsigned int* sorted = reinterpret_cast<unsigned int*>(ubuf);       // CH*4 = 16384 <= 17408
    unsigned short (*A_x)[AP] = reinterpret_cast<unsigned short (*)[AP]>(ubuf);

    int t = threadIdx.x;
    int b = blockIdx.x;
    int s = bstart[b], e = bstart[b + 1];
    int w = t >> 6, lane = t & 63;
    int lr = lane & 15, lk = lane >> 4;

    if (t < 2 * D) bn_lds[t] = 0.f;

    // ---------- agg phase ----------
    float a0[8], a1[8];
    #pragma unroll
    for (int i = 0; i < 8; ++i) { a0[i] = 0.f; a1[i] = 0.f; }
    const unsigned short* xb = xbf + lane * 2;

    for (int cs = s; cs < e; cs += CH) {
        int cnt = e - cs; if (cnt > CH) cnt = CH;
        if (t < BROWS) hist[t] = 0;
        __syncthreads();
        #pragma unroll
        for (int k = 0; k < CH / 512; ++k) {
            int i = k * 512 + t;
            if (i < cnt) atomicAdd(&hist[(binned[cs + i] >> 16) & (BROWS - 1)], 1);
        }
        __syncthreads();
        if (t < BROWS) sincl[t] = hist[t];
        __syncthreads();
        #pragma unroll
        for (int off = 1; off < BROWS; off <<= 1) {
            int u = 0;
            if (t < BROWS && t >= off) u = sincl[t - off];
            __syncthreads();
            if (t < BROWS) sincl[t] += u;
            __syncthreads();
        }
        if (t < BROWS) {
            int ex = sincl[t] - hist[t];
            sstart[t] = ex;
            scur[t] = ex;
        }
        if (t == 0) sstart[BROWS] = cnt;
        __syncthreads();
        #pragma unroll
        for (int k = 0; k < CH / 512; ++k) {
            int i = k * 512 + t;
            if (i < cnt) {
                unsigned int p = binned[cs + i];
                int pos = atomicAdd(&scur[(p >> 16) & (BROWS - 1)], 1);
                sorted[pos] = p;
            }
        }
        __syncthreads();
        // aggregate: wave w owns rows [w*8, w*8+8), 8-deep load unroll
        #pragma unroll
        for (int i = 0; i < 8; ++i) {
            int r = w * 8 + i;
            int js = sstart[r], je = sstart[r + 1];
            float s0 = a0[i], s1 = a1[i];
            int j = js;
            for (; j + 8 <= je; j += 8) {
                unsigned int v[8];
                #pragma unroll
                for (int q = 0; q < 8; ++q)
                    v[q] = *reinterpret_cast<const unsigned int*>(
                        xb + (size_t)(sorted[j + q] & 0xFFFFu) * D);
                #pragma unroll
                for (int q = 0; q < 8; ++q) {
                    s0 += bf2f((unsigned short)v[q]);
                    s1 += bf2f((unsigned short)(v[q] >> 16));
                }
            }
            if (j + 4 <= je) {
                unsigned int v[4];
                #pragma unroll
                for (int q = 0; q < 4; ++q)
                    v[q] = *reinterpret_cast<const unsigned int*>(
                        xb + (size_t)(sorted[j + q] & 0xFFFFu) * D);
                #pragma unroll
                for (int q = 0; q < 4; ++q) {
                    s0 += bf2f((unsigned short)v[q]);
                    s1 += bf2f((unsigned short)(v[q] >> 16));
                }
                j += 4;
            }
            for (; j < je; ++j) {
                unsigned int v = *reinterpret_cast<const unsigned int*>(
                    xb + (size_t)(sorted[j] & 0xFFFFu) * D);
                s0 += bf2f((unsigned short)v);
                s1 += bf2f((unsigned short)(v >> 16));
            }
            a0[i] = s0; a1[i] = s1;
        }
        __syncthreads();   // all waves done reading sorted for this chunk
    }

    // ---------- write agg -> A_agg (LDS), hoist B, stage x -> A_x ----------
    #pragma unroll
    for (int i = 0; i < 8; ++i) {
        int r = w * 8 + i;
        unsigned int o = (unsigned int)f2bf(a0[i]) | ((unsigned int)f2bf(a1[i]) << 16);
        *reinterpret_cast<unsigned int*>(&A_agg[r][lane * 2]) = o;
    }
    // B fragments: wave w cols [w*16, w*16+16), k = ks*32 + lk*8
    bf16x8 Breg[8];
    #pragma unroll
    for (int ks = 0; ks < 8; ++ks)
        Breg[ks] = *reinterpret_cast<const bf16x8*>(
            &Wcat[(w * 16 + lr) * 256 + ks * 32 + lk * 8]);
    // x rows -> A_x (overwrites sorted; safe: all waves passed the final barrier)
    #pragma unroll
    for (int k = 0; k < 2; ++k) {
        int ch = k * 512 + t;          // 0..1023
        int r = ch >> 4;               // 0..63
        int c16 = ch & 15;             // 16B chunk
        int node = b * BROWS + r;
        ushort8 v = (ushort8){0, 0, 0, 0, 0, 0, 0, 0};
        if (node < N) v = *reinterpret_cast<const ushort8*>(&xbf[(size_t)node * D + c16 * 8]);
        *reinterpret_cast<ushort8*>(&A_x[r][c16 * 8]) = v;
    }
    __syncthreads();

    // ---------- MFMA: acc[m] over K=256 (agg half + x half) ----------
    f32x4 acc[4];
    #pragma unroll
    for (int m = 0; m < 4; ++m) acc[m] = (f32x4){0.f, 0.f, 0.f, 0.f};
    #pragma unroll
    for (int m = 0; m < 4; ++m) {
        #pragma unroll
        for (int ks = 0; ks < 4; ++ks) {
            bf16x8 a = *reinterpret_cast<const bf16x8*>(&A_agg[m * 16 + lr][ks * 32 + lk * 8]);
            acc[m] = __builtin_amdgcn_mfma_f32_16x16x32_bf16(a, Breg[ks], acc[m], 0, 0, 0);
        }
        #pragma unroll
        for (int ks = 0; ks < 4; ++ks) {
            bf16x8 a = *reinterpret_cast<const bf16x8*>(&A_x[m * 16 + lr][ks * 32 + lk * 8]);
            acc[m] = __builtin_amdgcn_mfma_f32_16x16x32_bf16(a, Breg[ks + 4], acc[m], 0, 0, 0);
        }
    }

    // ---------- epilogue: bias + relu + store bf16 h + BN partials ----------
    int colo = w * 16 + lr;
    float bias = bl[colo] + br[colo];
    float s1 = 0.f, s2 = 0.f;
    #pragma unroll
    for (int m = 0; m < 4; ++m)
        #pragma unroll
        for (int ee = 0; ee < 4; ++ee) {
            int node = b * BROWS + m * 16 + lk * 4 + ee;
            if (node < N) {
                float hv = acc[m][ee] + bias;
                hv = hv > 0.f ? hv : 0.f;
                hbf[(size_t)node * D + colo] = f2bf(hv);
                s1 += hv;
                s2 += hv * hv;
            }
        }
    atomicAdd(&bn_lds[colo], s1);
    atomicAdd(&bn_lds[D + colo], s2);
    __syncthreads();
    if (t < D) {
        atomicAdd(&bn_sum[t], bn_lds[t]);
        atomicAdd(&bn_ss[t], bn_lds[D + t]);
    }
}

// ---- bnfin: per-channel scale/shift ---------------------------------------
__global__ void bnfin_k(const float* __restrict__ bn_sum, const float* __restrict__ bn_ss,
                        const float* __restrict__ gamma, const float* __restrict__ beta,
                        float* __restrict__ scale, float* __restrict__ shift, float invN) {
    int d = threadIdx.x;
    float m = bn_sum[d] * invN;
    float v = bn_ss[d] * invN - m * m;
    float r = rsqrtf(v + 1e-5f);
    float sc = gamma[d] * r;
    scale[d] = sc;
    shift[d] = beta[d] - m * sc;
}

// ---- bnapply: out = h*scale + shift (h bf16 -> f32 out) -------------------
__global__ __launch_bounds__(256) void bnapply_k(const unsigned short* __restrict__ hbf,
                                                 float* __restrict__ out,
                                                 const float* __restrict__ scale,
                                                 const float* __restrict__ shift,
                                                 int total8) {
    int gid = blockIdx.x * 256 + threadIdx.x;
    if (gid >= total8) return;
    int d8 = (gid & 15) * 8;
    ushort8 hv = *reinterpret_cast<const ushort8*>(&hbf[(size_t)gid * 8]);
    float4 sc0 = *reinterpret_cast<const float4*>(scale + d8);
    float4 sc1 = *reinterpret_cast<const float4*>(scale + d8 + 4);
    float4 sh0 = *reinterpret_cast<const float4*>(shift + d8);
    float4 sh1 = *reinterpret_cast<const float4*>(shift + d8 + 4);
    float4 o0, o1;
    o0.x = bf2f((unsigned short)hv[0]) * sc0.x + sh0.x;
    o0.y = bf2f((unsigned short)hv[1]) * sc0.y + sh0.y;
    o0.z = bf2f((unsigned short)hv[2]) * sc0.z + sh0.z;
    o0.w = bf2f((unsigned short)hv[3]) * sc0.w + sh0.w;
    o1.x = bf2f((unsigned short)hv[4]) * sc1.x + sh1.x;
    o1.y = bf2f((unsigned short)hv[5]) * sc1.y + sh1.y;
    o1.z = bf2f((unsigned short)hv[6]) * sc1.z + sh1.z;
    o1.w = bf2f((unsigned short)hv[7]) * sc1.w + sh1.w;
    *reinterpret_cast<float4*>(out + (size_t)gid * 8) = o0;
    *reinterpret_cast<float4*>(out + (size_t)gid * 8 + 4) = o1;
}

extern "C" void kernel_launch(void* const* d_in, const int* in_sizes, int n_in,
                              void* d_out, int out_size, void* d_ws, size_t ws_size,
                              hipStream_t stream) {
    const float* x     = (const float*)d_in[0];
    const int*   ei    = (const int*)d_in[1];
    const float* Wl    = (const float*)d_in[2];
    const float* bl    = (const float*)d_in[3];
    const float* Wr    = (const float*)d_in[4];
    const float* br    = (const float*)d_in[5];
    const float* gamma = (const float*)d_in[6];
    const float* beta  = (const float*)d_in[7];
    int N = in_sizes[0] / D;
    int E = in_sizes[1] / 2;
    int NB = (N + BROWS - 1) / BROWS;    // 782 (must be <= 1024)
    int eblocks = (E + 8191) / 8192;     // 98 (must be <= 128)

    float* ws = (float*)d_ws;
    float* bn_sum = ws;                                   // D
    float* bn_ss  = ws + D;                               // D
    float* scale  = ws + 2 * D;                           // D
    float* shift  = ws + 3 * D;                           // D
    unsigned short* xbf  = (unsigned short*)(ws + 4 * D); // N*D
    unsigned short* hbf  = xbf + (size_t)N * D;           // N*D
    unsigned short* Wcat = hbf + (size_t)N * D;           // 2*D*D
    int* gcur   = (int*)(Wcat + 2 * D * D);               // pad 1024
    int* bstart = gcur + 1024;                            // pad 1028
    int* ghT    = bstart + 1028;                          // 1024*128
    unsigned int* binned = (unsigned int*)(ghT + 1024 * 128); // E
    float* out = (float*)d_out;

    const int* rowi = ei;
    const int* coli = ei + E;

    setup_k<<<2048, 256, 0, stream>>>(x, Wl, Wr, rowi, xbf, Wcat, ghT, bn_sum,
                                      N, NB, E, eblocks);
    scanB_k<<<1, 1024, 0, stream>>>(ghT, bstart, gcur, NB, E, eblocks);
    binB_k<<<eblocks, 256, 0, stream>>>(rowi, coli, gcur, binned, E, NB);
    aggemm_k<<<NB, 512, 0, stream>>>(xbf, binned, bstart, Wcat, bl, br,
                                     hbf, bn_sum, bn_ss, N);
    bnfin_k<<<1, D, 0, stream>>>(bn_sum, bn_ss, gamma, beta, scale, shift,
                                 1.0f / (float)N);
    int total8 = N * D / 8;
    bnapply_k<<<(total8 + 255) / 256, 256, 0, stream>>>(hbf, out, scale, shift, total8);
}